// Round 5
// baseline (142.064 us; speedup 1.0000x reference)
//
#include <hip/hip_runtime.h>

#define NPTS  8192
#define BATCH 4

typedef short  bf8   __attribute__((ext_vector_type(8)));   // 8 bf16 = 4 VGPRs
typedef float  f32x4 __attribute__((ext_vector_type(4)));
typedef float  v2f   __attribute__((ext_vector_type(2)));

__device__ inline unsigned short bf16_rne(float x) {
    unsigned u = __float_as_uint(x);
    unsigned r = (u + 0x7FFFu + ((u >> 16) & 1u)) >> 16;   // round-nearest-even
    return (unsigned short)r;
}
__device__ inline float bf16_to_f(unsigned short h) {
    return __uint_as_float(((unsigned)h) << 16);
}

// ============================================================================
// MFMA path. Identity: ||s-d||^2 = -2*(s.d + w_s + w_d), w_p = -0.5*||p||^2.
// K-slot layout (k0..15, k16..31 zero):
//   A(point s): [s_xh s_yh s_zh  s_xl s_yl s_zl  s_xh s_yh | s_zh 1 1 w_h w_l 0 0 0]
//   B(point d): [d_xh d_yh d_zh  d_xh d_yh d_zh  d_xl d_yl | d_zl w_h w_l 1 1 0 0 0]
//   => sum_k A_k B_k = s_hi.d_hi + s_lo.d_hi + s_hi.d_lo + w_d + w_s
//      (missing s_lo.d_lo ~ 2^-18 — negligible)
// One mfma_f32_16x16x32_bf16 per 16n x 16m tile => C = s.d + w_s + w_d,
// dist = -2*C; per-n min over m == row-max of C. Two passes (A/B swapped)
// give both chamfer directions.
// Fragment storage (per cloud per role): [b][tile][slot<32] x 16B,
// slot = (k_half<<4) | (point&15); lanes>=32 (k 16..31) use zero frags.
// ============================================================================

__global__ void pack_mfma(const float* __restrict__ f, const float* __restrict__ f_,
                          bf8* __restrict__ fA, bf8* __restrict__ fB,
                          bf8* __restrict__ gA, bf8* __restrict__ gB,
                          float* __restrict__ out) {
    int j = blockIdx.x * blockDim.x + threadIdx.x;   // 0..65535
    if (j == 0) out[0] = 0.0f;                       // d_out poisoned 0xAA
    int cloud = j >> 15;
    int idx   = j & 32767;                           // b*8192 + p
    const float* src = cloud ? f_ : f;
    float x = src[idx * 3 + 0], y = src[idx * 3 + 1], z = src[idx * 3 + 2];
    float w = -0.5f * (x * x + y * y + z * z);
    unsigned short xh = bf16_rne(x), yh = bf16_rne(y), zh = bf16_rne(z);
    unsigned short xl = bf16_rne(x - bf16_to_f(xh));
    unsigned short yl = bf16_rne(y - bf16_to_f(yh));
    unsigned short zl = bf16_rne(z - bf16_to_f(zh));
    unsigned short wh = bf16_rne(w);
    unsigned short wl = bf16_rne(w - bf16_to_f(wh));
    const short ONE = (short)0x3F80;                 // bf16 1.0

    bf8 A0, A1, B0, B1;
    A0[0]=(short)xh; A0[1]=(short)yh; A0[2]=(short)zh; A0[3]=(short)xl;
    A0[4]=(short)yl; A0[5]=(short)zl; A0[6]=(short)xh; A0[7]=(short)yh;
    A1[0]=(short)zh; A1[1]=ONE;       A1[2]=ONE;       A1[3]=(short)wh;
    A1[4]=(short)wl; A1[5]=0;         A1[6]=0;         A1[7]=0;
    B0[0]=(short)xh; B0[1]=(short)yh; B0[2]=(short)zh; B0[3]=(short)xh;
    B0[4]=(short)yh; B0[5]=(short)zh; B0[6]=(short)xl; B0[7]=(short)yl;
    B1[0]=(short)zl; B1[1]=(short)wh; B1[2]=(short)wl; B1[3]=ONE;
    B1[4]=ONE;       B1[5]=0;         B1[6]=0;         B1[7]=0;

    int b = idx >> 13, p = idx & 8191;
    int t = p >> 4, li = p & 15;
    size_t slot = ((size_t)(b * 512 + t)) * 32;
    bf8* Adst = cloud ? gA : fA;
    bf8* Bdst = cloud ? gB : fB;
    Adst[slot + li]      = A0;
    Adst[slot + 16 + li] = A1;
    Bdst[slot + li]      = B0;
    Bdst[slot + 16 + li] = B1;
}

// 1024 blocks x 256 thr (4 waves). Block = (pass, b, nblk of 256 rows, mseg of
// 2048 m). Wave: 4 strips of 16 rows, streams 128 B-tiles; per tile: 1 frag
// load + 4 MFMA + 4 vec-max. All 4 waves stream identical B tiles -> L1 reuse.
__global__ __launch_bounds__(256) void chamfer_mfma(
        const bf8* __restrict__ fA, const bf8* __restrict__ fB,
        const bf8* __restrict__ gA, const bf8* __restrict__ gB,
        float* __restrict__ seg) {
    int tid  = threadIdx.x;
    int wv   = tid >> 6, lane = tid & 63;
    int bx   = blockIdx.x;
    int mseg = bx & 3;
    int nblk = (bx >> 2) & 31;
    int b    = (bx >> 7) & 3;
    int pass = bx >> 9;

    const bf8* __restrict__ Af = pass ? gA : fA;   // rows (query side)
    const bf8* __restrict__ Bf = pass ? fB : gB;   // cols (target side)

    bf8 zero = {};
    bf8 a[4];
    f32x4 rmax[4];
    int nt_base = b * 512 + nblk * 16 + wv * 4;
#pragma unroll
    for (int s = 0; s < 4; ++s) {
        a[s] = (lane < 32) ? Af[(size_t)(nt_base + s) * 32 + lane] : zero;
        rmax[s] = (f32x4)(-3.0e38f);
    }

    const bf8* __restrict__ bp = Bf + ((size_t)(b * 512 + mseg * 128)) * 32;
    bf8 bq = (lane < 32) ? bp[lane] : zero;
    f32x4 zc = (f32x4)(0.0f);

    for (int i = 0; i < 128; ++i) {
        int ip = (i + 1 < 128) ? i + 1 : 127;      // tail: redundant reload
        bf8 nx = (lane < 32) ? bp[(size_t)ip * 32 + lane] : zero;
#pragma unroll
        for (int s = 0; s < 4; ++s) {
            f32x4 d = __builtin_amdgcn_mfma_f32_16x16x32_bf16(a[s], bq, zc, 0, 0, 0);
            rmax[s] = __builtin_elementwise_max(rmax[s], d);
        }
        bq = nx;
    }

    // Row-max across the 16 cols: butterfly within 16-lane groups.
#pragma unroll
    for (int s = 0; s < 4; ++s) {
#pragma unroll
        for (int m = 1; m < 16; m <<= 1) {
            f32x4 o;
            o[0] = __shfl_xor(rmax[s][0], m, 64);
            o[1] = __shfl_xor(rmax[s][1], m, 64);
            o[2] = __shfl_xor(rmax[s][2], m, 64);
            o[3] = __shfl_xor(rmax[s][3], m, 64);
            rmax[s] = __builtin_elementwise_max(rmax[s], o);
        }
    }

    // C/D row = (lane>>4)*4 + reg; lanes 0,16,32,48 write 4 rows each.
    if ((lane & 15) == 0) {
        int quad = lane >> 4;
        float* sg = seg + ((size_t)((pass * 4 + b) * 4 + mseg)) * NPTS
                        + nblk * 256 + wv * 64;
#pragma unroll
        for (int s = 0; s < 4; ++s)
#pragma unroll
            for (int r = 0; r < 4; ++r)
                sg[s * 16 + quad * 4 + r] = rmax[s][r];
    }
}

__global__ __launch_bounds__(1024) void finalize_mfma(
        const float* __restrict__ seg, float* __restrict__ out) {
    __shared__ float partial[16];
    int j  = blockIdx.x * 1024 + threadIdx.x;   // 0..65535: (pass*4+b)*8192+n
    int pb = j >> 13;
    int n  = j & 8191;
    float emax = -3.0e38f;
#pragma unroll
    for (int q = 0; q < 4; ++q)
        emax = fmaxf(emax, seg[((size_t)(pb * 4 + q)) * NPTS + n]);
    float dist = fmaxf(-2.0f * emax, 0.0f);
    for (int off = 32; off > 0; off >>= 1)
        dist += __shfl_down(dist, off, 64);
    int lane = threadIdx.x & 63, wv = threadIdx.x >> 6;
    if (lane == 0) partial[wv] = dist;
    __syncthreads();
    if (threadIdx.x < 16) {
        float s = partial[threadIdx.x];
        for (int off = 8; off > 0; off >>= 1)
            s += __shfl_down(s, off, 64);
        if (threadIdx.x == 0) atomicAdd(out, s * (1.0f / 32768.0f));
    }
}

// ============================================================================
// Fallback 1 (ws >= 3MB): verified R4 packed-fp32 path (45.7 us main).
// ============================================================================

__global__ void pack_pk(const float* __restrict__ f, const float* __restrict__ f_,
                        float4* __restrict__ pk, float* __restrict__ prf,
                        float* __restrict__ out) {
    int j = blockIdx.x * blockDim.x + threadIdx.x;
    if (j == 0) out[0] = 0.0f;
    const float* src = (j >= 32768) ? f_ : f;
    int idx = j & 32767;
    float x = src[idx * 3 + 0], y = src[idx * 3 + 1], z = src[idx * 3 + 2];
    float w = -0.5f * (x * x + y * y + z * z);
    pk[j] = make_float4(x, y, z, w);
    int  slot = j & 1;
    long base = (long)(j >> 1) * 8;
    prf[base + 0 + slot] = x;
    prf[base + 2 + slot] = y;
    prf[base + 4 + slot] = z;
    prf[base + 6 + slot] = w;
}

__global__ __launch_bounds__(512, 8) void chamfer_pk(
        const float4* __restrict__ pk, const float4* __restrict__ pr,
        float* __restrict__ seg) {
    __shared__ float red[8][256];
    int tid  = threadIdx.x;
    int wv   = __builtin_amdgcn_readfirstlane(tid >> 6);
    int lane = tid & 63;
    int bx   = blockIdx.x;
    int tile = bx & 31;
    int b    = (bx >> 5) & 3;
    int dir  = (bx >> 7) & 1;
    int mq   = bx >> 8;

    const float4* __restrict__ A = pk + ((size_t)dir * BATCH + b) * NPTS;
    int n_base = tile * 256;
    v2f px[4], py[4], pz[4], e2[4];
#pragma unroll
    for (int r = 0; r < 4; ++r) {
        float4 p = A[n_base + lane + 64 * r];
        px[r] = (v2f){p.x, p.x};
        py[r] = (v2f){p.y, p.y};
        pz[r] = (v2f){p.z, p.z};
        e2[r] = (v2f){-1e30f, -1e30f};
    }
    int sb_m = (1 - dir) * BATCH + b;
    const float4* __restrict__ mp =
        pr + ((size_t)sb_m * 4096 + mq * 1024 + wv * 128) * 2;

    for (int i = 0; i < 128; i += 4) {
#pragma unroll
        for (int u = 0; u < 4; ++u) {
            float4 qa = mp[(i + u) * 2 + 0];
            float4 qb = mp[(i + u) * 2 + 1];
            v2f qx = (v2f){qa.x, qa.y};
            v2f qy = (v2f){qa.z, qa.w};
            v2f qz = (v2f){qb.x, qb.y};
            v2f qw = (v2f){qb.z, qb.w};
#pragma unroll
            for (int r = 0; r < 4; ++r) {
                v2f c = __builtin_elementwise_fma(px[r], qx, qw);
                c = __builtin_elementwise_fma(py[r], qy, c);
                c = __builtin_elementwise_fma(pz[r], qz, c);
                e2[r] = __builtin_elementwise_max(e2[r], c);
            }
        }
    }
#pragma unroll
    for (int r = 0; r < 4; ++r)
        red[wv][lane + 64 * r] = fmaxf(e2[r].x, e2[r].y);
    __syncthreads();
    if (tid < 256) {
        float emax = red[0][tid];
#pragma unroll
        for (int ww = 1; ww < 8; ++ww) emax = fmaxf(emax, red[ww][tid]);
        seg[mq * (2 * BATCH * NPTS) + dir * (BATCH * NPTS) + b * NPTS
            + n_base + tid] = emax;
    }
}

__global__ __launch_bounds__(1024) void finalize_pk(
        const float4* __restrict__ pk, const float* __restrict__ seg,
        float* __restrict__ out) {
    __shared__ float partial[16];
    int j = blockIdx.x * 1024 + threadIdx.x;
    float emax = seg[j];
#pragma unroll
    for (int q = 1; q < 4; ++q) emax = fmaxf(emax, seg[q * 65536 + j]);
    float dist = fmaxf(-2.0f * (emax + pk[j].w), 0.0f);
    for (int off = 32; off > 0; off >>= 1)
        dist += __shfl_down(dist, off, 64);
    int lane = threadIdx.x & 63, wv = threadIdx.x >> 6;
    if (lane == 0) partial[wv] = dist;
    __syncthreads();
    if (threadIdx.x < 16) {
        float s = partial[threadIdx.x];
        for (int off = 8; off > 0; off >>= 1)
            s += __shfl_down(s, off, 64);
        if (threadIdx.x == 0) atomicAdd(out, s * (1.0f / 32768.0f));
    }
}

// ============================================================================
// Fallback 2 (no ws): verified R2 kernel.
// ============================================================================

__global__ void zero_out_kernel(float* __restrict__ out) { out[0] = 0.0f; }

__global__ __launch_bounds__(1024) void chamfer_fallback(
        const float* __restrict__ f, const float* __restrict__ f_,
        float* __restrict__ out) {
    __shared__ float wlds[NPTS];
    __shared__ float red[16][256];
    __shared__ float partial[4];
    int tid  = threadIdx.x;
    int wv   = __builtin_amdgcn_readfirstlane(tid >> 6);
    int lane = tid & 63;
    int bx   = blockIdx.x;
    int dir  = bx >> 7;
    int b    = (bx >> 5) & 3;
    int tile = bx & 31;
    int n_base = tile * 256;
    const float* __restrict__ A  = dir ? f_ : f;
    const float* __restrict__ Bm = dir ? f  : f_;
    const float* an = A  + (size_t)b * NPTS * 3;
    const float* bm = Bm + (size_t)b * NPTS * 3;
    for (int i = tid; i < NPTS; i += 1024) {
        float x = bm[i * 3 + 0], y = bm[i * 3 + 1], z = bm[i * 3 + 2];
        wlds[i] = -0.5f * (x * x + y * y + z * z);
    }
    float xn[4], yn[4], zn[4];
#pragma unroll
    for (int r = 0; r < 4; ++r) {
        int n = n_base + lane + 64 * r;
        xn[r] = an[n * 3 + 0]; yn[r] = an[n * 3 + 1]; zn[r] = an[n * 3 + 2];
    }
    __syncthreads();
    float e[4];
#pragma unroll
    for (int r = 0; r < 4; ++r) e[r] = -1e30f;
    int m0 = wv * (NPTS / 16);
#pragma unroll 4
    for (int i = 0; i < NPTS / 16; ++i) {
        int m = m0 + i;
        float qx = bm[m * 3 + 0], qy = bm[m * 3 + 1], qz = bm[m * 3 + 2];
        float qw = wlds[m];
#pragma unroll
        for (int r = 0; r < 4; ++r) {
            float c = fmaf(zn[r], qz, fmaf(yn[r], qy, fmaf(xn[r], qx, qw)));
            e[r] = fmaxf(e[r], c);
        }
    }
#pragma unroll
    for (int r = 0; r < 4; ++r) red[wv][lane + 64 * r] = e[r];
    __syncthreads();
    if (tid < 256) {
        float emax = red[0][tid];
#pragma unroll
        for (int ww = 1; ww < 16; ++ww) emax = fmaxf(emax, red[ww][tid]);
        int n = n_base + tid;
        float x = an[n * 3 + 0], y = an[n * 3 + 1], z = an[n * 3 + 2];
        float dist = fmaxf(x * x + y * y + z * z - 2.0f * emax, 0.0f);
        for (int off = 32; off > 0; off >>= 1)
            dist += __shfl_down(dist, off, 64);
        if ((tid & 63) == 0) partial[tid >> 6] = dist;
    }
    __syncthreads();
    if (tid == 0) {
        float s = partial[0] + partial[1] + partial[2] + partial[3];
        atomicAdd(out, s * (1.0f / 32768.0f));
    }
}

extern "C" void kernel_launch(void* const* d_in, const int* in_sizes, int n_in,
                              void* d_out, int out_size, void* d_ws, size_t ws_size,
                              hipStream_t stream) {
    const float* f  = (const float*)d_in[0];
    const float* f_ = (const float*)d_in[1];
    float* out = (float*)d_out;

    const size_t MB = 1048576;
    if (ws_size >= 5 * MB) {
        bf8*   fA  = (bf8*)d_ws;                        // f  as A-role, 1 MB
        bf8*   fB  = (bf8*)((char*)d_ws + 1 * MB);      // f  as B-role
        bf8*   gA  = (bf8*)((char*)d_ws + 2 * MB);      // f_ as A-role
        bf8*   gB  = (bf8*)((char*)d_ws + 3 * MB);      // f_ as B-role
        float* seg = (float*)((char*)d_ws + 4 * MB);    // 1 MB
        pack_mfma<<<256, 256, 0, stream>>>(f, f_, fA, fB, gA, gB, out);
        chamfer_mfma<<<1024, 256, 0, stream>>>(fA, fB, gA, gB, seg);
        finalize_mfma<<<64, 1024, 0, stream>>>(seg, out);
    } else if (ws_size >= 3 * MB) {
        float4* pk = (float4*)d_ws;
        float4* pr = (float4*)((char*)d_ws + 1 * MB);
        float*  sg = (float*)((char*)d_ws + 2 * MB);
        pack_pk<<<256, 256, 0, stream>>>(f, f_, pk, (float*)pr, out);
        chamfer_pk<<<1024, 512, 0, stream>>>(pk, pr, sg);
        finalize_pk<<<64, 1024, 0, stream>>>(pk, sg, out);
    } else {
        zero_out_kernel<<<1, 1, 0, stream>>>(out);
        chamfer_fallback<<<256, 1024, 0, stream>>>(f, f_, out);
    }
}

// Round 6
// 111.439 us; speedup vs baseline: 1.2748x; 1.2748x over previous
//
#include <hip/hip_runtime.h>

#define NPTS  8192
#define BATCH 4

typedef short  bf8   __attribute__((ext_vector_type(8)));   // 8 bf16 = 4 VGPRs
typedef float  f32x4 __attribute__((ext_vector_type(4)));
typedef float  v2f   __attribute__((ext_vector_type(2)));

__device__ inline unsigned short bf16_rne(float x) {
    unsigned u = __float_as_uint(x);
    unsigned r = (u + 0x7FFFu + ((u >> 16) & 1u)) >> 16;   // round-nearest-even
    return (unsigned short)r;
}
__device__ inline float bf16_to_f(unsigned short h) {
    return __uint_as_float(((unsigned)h) << 16);
}

// ============================================================================
// MFMA path (layouts VERIFIED in R5: absmax 0.0).
// Identity: ||s-d||^2 = -2*(s.d + w_s + w_d), w_p = -0.5*||p||^2.
// K-slots 0..15:
//   A(point s): [xh yh zh xl yl zl xh yh | zh 1 1 wh wl 0 0 0]
//   B(point d): [xh yh zh xh yh zh xl yl | zl wh wl 1 1 0 0 0]
// K-slots 16..31 DUPLICATE 0..15 (lanes >=32 load frag[lane&31]) =>
//   C = 2*(s.d + w_s + w_d);  dist = max(-C, 0).  No cndmask, no zero frags.
// Fragment storage per role: [b][tile][slot<32] x 16B, slot=(khalf<<4)|(pt&15).
// ============================================================================

__global__ void pack_mfma(const float* __restrict__ f, const float* __restrict__ f_,
                          bf8* __restrict__ fA, bf8* __restrict__ fB,
                          bf8* __restrict__ gA, bf8* __restrict__ gB,
                          float* __restrict__ out) {
    int j = blockIdx.x * blockDim.x + threadIdx.x;   // 0..65535
    if (j == 0) out[0] = 0.0f;                       // d_out poisoned 0xAA
    int cloud = j >> 15;
    int idx   = j & 32767;                           // b*8192 + p
    const float* src = cloud ? f_ : f;
    float x = src[idx * 3 + 0], y = src[idx * 3 + 1], z = src[idx * 3 + 2];
    float w = -0.5f * (x * x + y * y + z * z);
    unsigned short xh = bf16_rne(x), yh = bf16_rne(y), zh = bf16_rne(z);
    unsigned short xl = bf16_rne(x - bf16_to_f(xh));
    unsigned short yl = bf16_rne(y - bf16_to_f(yh));
    unsigned short zl = bf16_rne(z - bf16_to_f(zh));
    unsigned short wh = bf16_rne(w);
    unsigned short wl = bf16_rne(w - bf16_to_f(wh));
    const short ONE = (short)0x3F80;                 // bf16 1.0

    bf8 A0, A1, B0, B1;
    A0[0]=(short)xh; A0[1]=(short)yh; A0[2]=(short)zh; A0[3]=(short)xl;
    A0[4]=(short)yl; A0[5]=(short)zl; A0[6]=(short)xh; A0[7]=(short)yh;
    A1[0]=(short)zh; A1[1]=ONE;       A1[2]=ONE;       A1[3]=(short)wh;
    A1[4]=(short)wl; A1[5]=0;         A1[6]=0;         A1[7]=0;
    B0[0]=(short)xh; B0[1]=(short)yh; B0[2]=(short)zh; B0[3]=(short)xh;
    B0[4]=(short)yh; B0[5]=(short)zh; B0[6]=(short)xl; B0[7]=(short)yl;
    B1[0]=(short)zl; B1[1]=(short)wh; B1[2]=(short)wl; B1[3]=ONE;
    B1[4]=ONE;       B1[5]=0;         B1[6]=0;         B1[7]=0;

    int b = idx >> 13, p = idx & 8191;
    int t = p >> 4, li = p & 15;
    size_t slot = ((size_t)(b * 512 + t)) * 32;
    bf8* Adst = cloud ? gA : fA;
    bf8* Bdst = cloud ? gB : fB;
    Adst[slot + li]      = A0;
    Adst[slot + 16 + li] = A1;
    Bdst[slot + li]      = B0;
    Bdst[slot + 16 + li] = B1;
}

// 1024 blocks x 256 thr (4 waves). Block = (pass, b, nblk: 256 rows, mseg: 2048 m).
// Wave: 4 n-tiles; 64 pair-iters over m-tiles. Per iter: 2 unconditional frag
// loads (2-deep prefetch), 8 MFMA, 16 v_max3. All loads lane&31-indexed (K-dup).
__global__ __launch_bounds__(256) void chamfer_mfma(
        const bf8* __restrict__ fA, const bf8* __restrict__ fB,
        const bf8* __restrict__ gA, const bf8* __restrict__ gB,
        float* __restrict__ seg) {
    int tid  = threadIdx.x;
    int wv   = tid >> 6, lane = tid & 63, li = lane & 31;
    int bx   = blockIdx.x;
    int mseg = bx & 3;
    int nblk = (bx >> 2) & 31;
    int b    = (bx >> 7) & 3;
    int pass = bx >> 9;

    const bf8* __restrict__ Af = pass ? gA : fA;   // rows (query side)
    const bf8* __restrict__ Bf = pass ? fB : gB;   // cols (target side)

    bf8 a[4];
    f32x4 rmax[4];
    int nt_base = b * 512 + nblk * 16 + wv * 4;
#pragma unroll
    for (int s = 0; s < 4; ++s) {
        a[s] = Af[(size_t)(nt_base + s) * 32 + li];
        rmax[s] = (f32x4)(-3.0e38f);
    }

    const bf8* __restrict__ bp = Bf + ((size_t)(b * 512 + mseg * 128)) * 32;
    // 2-deep pair prefetch (pair = 2 m-tiles = 64 frag slots)
    bf8 q0a = bp[li],       q0b = bp[32 + li];
    bf8 q1a = bp[64 + li],  q1b = bp[96 + li];
    f32x4 zc = (f32x4)(0.0f);

#pragma unroll 2
    for (int i = 0; i < 64; ++i) {
        bf8 ca = q0a, cb = q0b;
        q0a = q1a; q0b = q1b;
        int nx = (i + 2 < 64) ? (i + 2) : 63;      // tail: redundant reload
        q1a = bp[(size_t)nx * 64 + li];
        q1b = bp[(size_t)nx * 64 + 32 + li];
#pragma unroll
        for (int s = 0; s < 4; ++s) {
            f32x4 d0 = __builtin_amdgcn_mfma_f32_16x16x32_bf16(a[s], ca, zc, 0, 0, 0);
            f32x4 d1 = __builtin_amdgcn_mfma_f32_16x16x32_bf16(a[s], cb, zc, 0, 0, 0);
            rmax[s] = __builtin_elementwise_max(
                          __builtin_elementwise_max(rmax[s], d0), d1);  // v_max3
        }
    }

    // Row-max across the 16 cols: butterfly within 16-lane groups.
#pragma unroll
    for (int s = 0; s < 4; ++s) {
#pragma unroll
        for (int m = 1; m < 16; m <<= 1) {
            f32x4 o;
            o[0] = __shfl_xor(rmax[s][0], m, 64);
            o[1] = __shfl_xor(rmax[s][1], m, 64);
            o[2] = __shfl_xor(rmax[s][2], m, 64);
            o[3] = __shfl_xor(rmax[s][3], m, 64);
            rmax[s] = __builtin_elementwise_max(rmax[s], o);
        }
    }

    // C/D row = (lane>>4)*4 + reg; lanes 0,16,32,48 write 4 rows each.
    if ((lane & 15) == 0) {
        int quad = lane >> 4;
        float* sg = seg + ((size_t)((pass * 4 + b) * 4 + mseg)) * NPTS
                        + nblk * 256 + wv * 64;
#pragma unroll
        for (int s = 0; s < 4; ++s)
#pragma unroll
            for (int r = 0; r < 4; ++r)
                sg[s * 16 + quad * 4 + r] = rmax[s][r];
    }
}

__global__ __launch_bounds__(1024) void finalize_mfma(
        const float* __restrict__ seg, float* __restrict__ out) {
    __shared__ float partial[16];
    int j  = blockIdx.x * 1024 + threadIdx.x;   // 0..65535: (pass*4+b)*8192+n
    int pb = j >> 13;
    int n  = j & 8191;
    float emax = -3.0e38f;
#pragma unroll
    for (int q = 0; q < 4; ++q)
        emax = fmaxf(emax, seg[((size_t)(pb * 4 + q)) * NPTS + n]);
    float dist = fmaxf(-emax, 0.0f);            // C already holds 2x payload
    for (int off = 32; off > 0; off >>= 1)
        dist += __shfl_down(dist, off, 64);
    int lane = threadIdx.x & 63, wv = threadIdx.x >> 6;
    if (lane == 0) partial[wv] = dist;
    __syncthreads();
    if (threadIdx.x < 16) {
        float s = partial[threadIdx.x];
        for (int off = 8; off > 0; off >>= 1)
            s += __shfl_down(s, off, 64);
        if (threadIdx.x == 0) atomicAdd(out, s * (1.0f / 32768.0f));
    }
}

// ============================================================================
// Fallback 1 (ws >= 3MB): verified R4 packed-fp32 path (45.7 us main).
// ============================================================================

__global__ void pack_pk(const float* __restrict__ f, const float* __restrict__ f_,
                        float4* __restrict__ pk, float* __restrict__ prf,
                        float* __restrict__ out) {
    int j = blockIdx.x * blockDim.x + threadIdx.x;
    if (j == 0) out[0] = 0.0f;
    const float* src = (j >= 32768) ? f_ : f;
    int idx = j & 32767;
    float x = src[idx * 3 + 0], y = src[idx * 3 + 1], z = src[idx * 3 + 2];
    float w = -0.5f * (x * x + y * y + z * z);
    pk[j] = make_float4(x, y, z, w);
    int  slot = j & 1;
    long base = (long)(j >> 1) * 8;
    prf[base + 0 + slot] = x;
    prf[base + 2 + slot] = y;
    prf[base + 4 + slot] = z;
    prf[base + 6 + slot] = w;
}

__global__ __launch_bounds__(512, 8) void chamfer_pk(
        const float4* __restrict__ pk, const float4* __restrict__ pr,
        float* __restrict__ seg) {
    __shared__ float red[8][256];
    int tid  = threadIdx.x;
    int wv   = __builtin_amdgcn_readfirstlane(tid >> 6);
    int lane = tid & 63;
    int bx   = blockIdx.x;
    int tile = bx & 31;
    int b    = (bx >> 5) & 3;
    int dir  = (bx >> 7) & 1;
    int mq   = bx >> 8;

    const float4* __restrict__ A = pk + ((size_t)dir * BATCH + b) * NPTS;
    int n_base = tile * 256;
    v2f px[4], py[4], pz[4], e2[4];
#pragma unroll
    for (int r = 0; r < 4; ++r) {
        float4 p = A[n_base + lane + 64 * r];
        px[r] = (v2f){p.x, p.x};
        py[r] = (v2f){p.y, p.y};
        pz[r] = (v2f){p.z, p.z};
        e2[r] = (v2f){-1e30f, -1e30f};
    }
    int sb_m = (1 - dir) * BATCH + b;
    const float4* __restrict__ mp =
        pr + ((size_t)sb_m * 4096 + mq * 1024 + wv * 128) * 2;

    for (int i = 0; i < 128; i += 4) {
#pragma unroll
        for (int u = 0; u < 4; ++u) {
            float4 qa = mp[(i + u) * 2 + 0];
            float4 qb = mp[(i + u) * 2 + 1];
            v2f qx = (v2f){qa.x, qa.y};
            v2f qy = (v2f){qa.z, qa.w};
            v2f qz = (v2f){qb.x, qb.y};
            v2f qw = (v2f){qb.z, qb.w};
#pragma unroll
            for (int r = 0; r < 4; ++r) {
                v2f c = __builtin_elementwise_fma(px[r], qx, qw);
                c = __builtin_elementwise_fma(py[r], qy, c);
                c = __builtin_elementwise_fma(pz[r], qz, c);
                e2[r] = __builtin_elementwise_max(e2[r], c);
            }
        }
    }
#pragma unroll
    for (int r = 0; r < 4; ++r)
        red[wv][lane + 64 * r] = fmaxf(e2[r].x, e2[r].y);
    __syncthreads();
    if (tid < 256) {
        float emax = red[0][tid];
#pragma unroll
        for (int ww = 1; ww < 8; ++ww) emax = fmaxf(emax, red[ww][tid]);
        seg[mq * (2 * BATCH * NPTS) + dir * (BATCH * NPTS) + b * NPTS
            + n_base + tid] = emax;
    }
}

__global__ __launch_bounds__(1024) void finalize_pk(
        const float4* __restrict__ pk, const float* __restrict__ seg,
        float* __restrict__ out) {
    __shared__ float partial[16];
    int j = blockIdx.x * 1024 + threadIdx.x;
    float emax = seg[j];
#pragma unroll
    for (int q = 1; q < 4; ++q) emax = fmaxf(emax, seg[q * 65536 + j]);
    float dist = fmaxf(-2.0f * (emax + pk[j].w), 0.0f);
    for (int off = 32; off > 0; off >>= 1)
        dist += __shfl_down(dist, off, 64);
    int lane = threadIdx.x & 63, wv = threadIdx.x >> 6;
    if (lane == 0) partial[wv] = dist;
    __syncthreads();
    if (threadIdx.x < 16) {
        float s = partial[threadIdx.x];
        for (int off = 8; off > 0; off >>= 1)
            s += __shfl_down(s, off, 64);
        if (threadIdx.x == 0) atomicAdd(out, s * (1.0f / 32768.0f));
    }
}

// ============================================================================
// Fallback 2 (no ws): verified R2 kernel.
// ============================================================================

__global__ void zero_out_kernel(float* __restrict__ out) { out[0] = 0.0f; }

__global__ __launch_bounds__(1024) void chamfer_fallback(
        const float* __restrict__ f, const float* __restrict__ f_,
        float* __restrict__ out) {
    __shared__ float wlds[NPTS];
    __shared__ float red[16][256];
    __shared__ float partial[4];
    int tid  = threadIdx.x;
    int wv   = __builtin_amdgcn_readfirstlane(tid >> 6);
    int lane = tid & 63;
    int bx   = blockIdx.x;
    int dir  = bx >> 7;
    int b    = (bx >> 5) & 3;
    int tile = bx & 31;
    int n_base = tile * 256;
    const float* __restrict__ A  = dir ? f_ : f;
    const float* __restrict__ Bm = dir ? f  : f_;
    const float* an = A  + (size_t)b * NPTS * 3;
    const float* bm = Bm + (size_t)b * NPTS * 3;
    for (int i = tid; i < NPTS; i += 1024) {
        float x = bm[i * 3 + 0], y = bm[i * 3 + 1], z = bm[i * 3 + 2];
        wlds[i] = -0.5f * (x * x + y * y + z * z);
    }
    float xn[4], yn[4], zn[4];
#pragma unroll
    for (int r = 0; r < 4; ++r) {
        int n = n_base + lane + 64 * r;
        xn[r] = an[n * 3 + 0]; yn[r] = an[n * 3 + 1]; zn[r] = an[n * 3 + 2];
    }
    __syncthreads();
    float e[4];
#pragma unroll
    for (int r = 0; r < 4; ++r) e[r] = -1e30f;
    int m0 = wv * (NPTS / 16);
#pragma unroll 4
    for (int i = 0; i < NPTS / 16; ++i) {
        int m = m0 + i;
        float qx = bm[m * 3 + 0], qy = bm[m * 3 + 1], qz = bm[m * 3 + 2];
        float qw = wlds[m];
#pragma unroll
        for (int r = 0; r < 4; ++r) {
            float c = fmaf(zn[r], qz, fmaf(yn[r], qy, fmaf(xn[r], qx, qw)));
            e[r] = fmaxf(e[r], c);
        }
    }
#pragma unroll
    for (int r = 0; r < 4; ++r) red[wv][lane + 64 * r] = e[r];
    __syncthreads();
    if (tid < 256) {
        float emax = red[0][tid];
#pragma unroll
        for (int ww = 1; ww < 16; ++ww) emax = fmaxf(emax, red[ww][tid]);
        int n = n_base + tid;
        float x = an[n * 3 + 0], y = an[n * 3 + 1], z = an[n * 3 + 2];
        float dist = fmaxf(x * x + y * y + z * z - 2.0f * emax, 0.0f);
        for (int off = 32; off > 0; off >>= 1)
            dist += __shfl_down(dist, off, 64);
        if ((tid & 63) == 0) partial[tid >> 6] = dist;
    }
    __syncthreads();
    if (tid == 0) {
        float s = partial[0] + partial[1] + partial[2] + partial[3];
        atomicAdd(out, s * (1.0f / 32768.0f));
    }
}

extern "C" void kernel_launch(void* const* d_in, const int* in_sizes, int n_in,
                              void* d_out, int out_size, void* d_ws, size_t ws_size,
                              hipStream_t stream) {
    const float* f  = (const float*)d_in[0];
    const float* f_ = (const float*)d_in[1];
    float* out = (float*)d_out;

    const size_t MB = 1048576;
    if (ws_size >= 5 * MB) {
        bf8*   fA  = (bf8*)d_ws;                        // f  as A-role, 1 MB
        bf8*   fB  = (bf8*)((char*)d_ws + 1 * MB);      // f  as B-role
        bf8*   gA  = (bf8*)((char*)d_ws + 2 * MB);      // f_ as A-role
        bf8*   gB  = (bf8*)((char*)d_ws + 3 * MB);      // f_ as B-role
        float* seg = (float*)((char*)d_ws + 4 * MB);    // 1 MB
        pack_mfma<<<256, 256, 0, stream>>>(f, f_, fA, fB, gA, gB, out);
        chamfer_mfma<<<1024, 256, 0, stream>>>(fA, fB, gA, gB, seg);
        finalize_mfma<<<64, 1024, 0, stream>>>(seg, out);
    } else if (ws_size >= 3 * MB) {
        float4* pk = (float4*)d_ws;
        float4* pr = (float4*)((char*)d_ws + 1 * MB);
        float*  sg = (float*)((char*)d_ws + 2 * MB);
        pack_pk<<<256, 256, 0, stream>>>(f, f_, pk, (float*)pr, out);
        chamfer_pk<<<1024, 512, 0, stream>>>(pk, pr, sg);
        finalize_pk<<<64, 1024, 0, stream>>>(pk, sg, out);
    } else {
        zero_out_kernel<<<1, 1, 0, stream>>>(out);
        chamfer_fallback<<<256, 1024, 0, stream>>>(f, f_, out);
    }
}